// Round 1
// baseline (1849.874 us; speedup 1.0000x reference)
//
#include <hip/hip_runtime.h>

#define SZ 128
#define NATOMS 100000
#define NBONDS 400000
#define NPAIRS 400000
#define NANG   800000

typedef float f32x4 __attribute__((ext_vector_type(4)));
typedef short s16x8 __attribute__((ext_vector_type(8)));

__device__ __forceinline__ unsigned short f2bf(float f) {
  union { float f; unsigned u; } v; v.f = f;
  unsigned r = v.u + 0x7FFFu + ((v.u >> 16) & 1u);
  return (unsigned short)(r >> 16);
}
__device__ __forceinline__ float bf2f(unsigned short h) {
  union { unsigned u; float f; } v; v.u = ((unsigned)h) << 16;
  return v.f;
}

// ---- workspace layout (bytes) ----
#define BOND_ANG_OFF 0ull
#define AGG_OFF      204800000ull
#define AGG2_OFF     256000000ull
#define H_OFF        307200000ull
#define H2_OFF       332800000ull
#define WT_BM_OFF    358400000ull
#define WT_SC_OFF    (WT_BM_OFF + 32768ull)
#define WT1_OFF      (WT_SC_OFF + 32768ull)
#define WT2_OFF      (WT1_OFF + 32768ull)
#define ZERO_BYTES   307200000ull   // bond_ang + agg + agg2 (contiguous)

// Pack W (f32 [k][n], k-major) into bf16 B-fragment order:
// chunk cid = (nt8*4 + kk)*64 + l holds W[kk*32+(l>>4)*8 + i][nt8*16 + (l&15)], i=0..7
__global__ __launch_bounds__(256) void k_prep_w(const float* __restrict__ W,
                                                s16x8* __restrict__ Wt) {
  int cid = blockIdx.x * 256 + threadIdx.x;   // 0..2047
  int nt8 = cid >> 8, kk = (cid >> 6) & 3, l = cid & 63;
  int col = nt8 * 16 + (l & 15);
  int k0  = kk * 32 + (l >> 4) * 8;
  s16x8 v;
#pragma unroll
  for (int i = 0; i < 8; ++i) v[i] = (short)f2bf(W[(k0 + i) * SZ + col]);
  Wt[cid] = v;
}

// LayerNorm f32 -> bf16, one wave per row (4 rows / 256-thread block)
__global__ __launch_bounds__(256) void k_ln(const float* __restrict__ x,
                                            const float* __restrict__ g,
                                            const float* __restrict__ bvec,
                                            unsigned short* __restrict__ hout) {
  int row  = blockIdx.x * 4 + (threadIdx.x >> 6);
  int lane = threadIdx.x & 63;
  float2 v = *(const float2*)(x + (size_t)row * SZ + lane * 2);
  float s = v.x + v.y, sq = v.x * v.x + v.y * v.y;
#pragma unroll
  for (int off = 32; off; off >>= 1) { s += __shfl_xor(s, off); sq += __shfl_xor(sq, off); }
  float m = s * 0.0078125f;
  float var = sq * 0.0078125f - m * m;
  float rstd = rsqrtf(var + 1e-5f);
  float2 gv = *(const float2*)(g + lane * 2);
  float2 bv = *(const float2*)(bvec + lane * 2);
  float y0 = (v.x - m) * rstd * gv.x + bv.x;
  float y1 = (v.y - m) * rstd * gv.y + bv.y;
  unsigned pack = (unsigned)f2bf(y0) | ((unsigned)f2bf(y1) << 16);
  ((unsigned*)hout)[(size_t)row * 64 + lane] = pack;
}

// bond_ang[idx] += angles  (102.4M f32 atomics)
__global__ __launch_bounds__(256) void k_angle_scatter(const float* __restrict__ angles,
                                                       const int* __restrict__ aidx,
                                                       float* __restrict__ bond_ang) {
  int id  = blockIdx.x * 256 + threadIdx.x;  // 25.6M threads
  int row = id >> 5;
  int c   = (id & 31) * 4;
  int b   = aidx[row];
  float4 v = *(const float4*)(angles + (size_t)row * SZ + c);
  float* p = bond_ang + (size_t)b * SZ + c;
  unsafeAtomicAdd(p + 0, v.x); unsafeAtomicAdd(p + 1, v.y);
  unsafeAtomicAdd(p + 2, v.z); unsafeAtomicAdd(p + 3, v.w);
}

// msg1: agg[dst] += relu((h[src] + bond_x + bond_ang) @ W_bm)
__global__ __launch_bounds__(256) void k_msg1(const unsigned short* __restrict__ h,
                                              const float* __restrict__ bx,
                                              const float* __restrict__ bang,
                                              const int* __restrict__ bidx,
                                              const s16x8* __restrict__ Wt,
                                              float* __restrict__ agg) {
  __shared__ s16x8 Wl[2048];   // 32KB, B-fragment order
  __shared__ s16x8 Tl[256];    // 4KB, A-fragment order (16 rows x 128 k)
  int tid = threadIdx.x;
  for (int i = tid; i < 2048; i += 256) Wl[i] = Wt[i];
  __syncthreads();
  int r = tid >> 4, kc = tid & 15;
  int w = tid >> 6, l = tid & 63;
  for (int tile = blockIdx.x; tile < NBONDS / 16; tile += gridDim.x) {
    int base = tile * 16;
    int b = base + r;
    int sidx = bidx[2 * b];
    uint4 hv = *(const uint4*)(h + (size_t)sidx * SZ + kc * 8);
    const unsigned short* hp = (const unsigned short*)&hv;
    float xb[8], ab[8];
    *(float4*)&xb[0] = *(const float4*)(bx + (size_t)b * SZ + kc * 8);
    *(float4*)&xb[4] = *(const float4*)(bx + (size_t)b * SZ + kc * 8 + 4);
    *(float4*)&ab[0] = *(const float4*)(bang + (size_t)b * SZ + kc * 8);
    *(float4*)&ab[4] = *(const float4*)(bang + (size_t)b * SZ + kc * 8 + 4);
    s16x8 tv;
#pragma unroll
    for (int i = 0; i < 8; ++i) tv[i] = (short)f2bf(bf2f(hp[i]) + xb[i] + ab[i]);
    Tl[(kc >> 2) * 64 + (kc & 3) * 16 + r] = tv;
    __syncthreads();
    f32x4 acc0 = {0.f, 0.f, 0.f, 0.f}, acc1 = {0.f, 0.f, 0.f, 0.f};
#pragma unroll
    for (int kk = 0; kk < 4; ++kk) {
      s16x8 av = Tl[kk * 64 + l];
      acc0 = __builtin_amdgcn_mfma_f32_16x16x32_bf16(av, Wl[((w * 2 + 0) * 4 + kk) * 64 + l], acc0, 0, 0, 0);
      acc1 = __builtin_amdgcn_mfma_f32_16x16x32_bf16(av, Wl[((w * 2 + 1) * 4 + kk) * 64 + l], acc1, 0, 0, 0);
    }
    int colb = w * 32 + (l & 15);
    int rowb = (l >> 4) * 4;
#pragma unroll
    for (int p = 0; p < 4; ++p) {
      int bb = base + rowb + p;
      int d = bidx[2 * bb + 1];
      unsafeAtomicAdd(agg + (size_t)d * SZ + colb,      fmaxf(acc0[p], 0.f));
      unsafeAtomicAdd(agg + (size_t)d * SZ + colb + 16, fmaxf(acc1[p], 0.f));
    }
    __syncthreads();
  }
}

// msg2: agg2[i] += relu((h2[i] + h2[j] + sc_pair) @ W_sc)
__global__ __launch_bounds__(256) void k_msg2(const unsigned short* __restrict__ h2,
                                              const float* __restrict__ scp,
                                              const int* __restrict__ sidx,
                                              const s16x8* __restrict__ Wt,
                                              float* __restrict__ agg2) {
  __shared__ s16x8 Wl[2048];
  __shared__ s16x8 Tl[256];
  int tid = threadIdx.x;
  for (int i = tid; i < 2048; i += 256) Wl[i] = Wt[i];
  __syncthreads();
  int r = tid >> 4, kc = tid & 15;
  int w = tid >> 6, l = tid & 63;
  for (int tile = blockIdx.x; tile < NPAIRS / 16; tile += gridDim.x) {
    int base = tile * 16;
    int b = base + r;
    int i0 = sidx[2 * b], j0 = sidx[2 * b + 1];
    uint4 hv1 = *(const uint4*)(h2 + (size_t)i0 * SZ + kc * 8);
    uint4 hv2 = *(const uint4*)(h2 + (size_t)j0 * SZ + kc * 8);
    const unsigned short* hp1 = (const unsigned short*)&hv1;
    const unsigned short* hp2 = (const unsigned short*)&hv2;
    float sb[8];
    *(float4*)&sb[0] = *(const float4*)(scp + (size_t)b * SZ + kc * 8);
    *(float4*)&sb[4] = *(const float4*)(scp + (size_t)b * SZ + kc * 8 + 4);
    s16x8 tv;
#pragma unroll
    for (int i = 0; i < 8; ++i) tv[i] = (short)f2bf(bf2f(hp1[i]) + bf2f(hp2[i]) + sb[i]);
    Tl[(kc >> 2) * 64 + (kc & 3) * 16 + r] = tv;
    __syncthreads();
    f32x4 acc0 = {0.f, 0.f, 0.f, 0.f}, acc1 = {0.f, 0.f, 0.f, 0.f};
#pragma unroll
    for (int kk = 0; kk < 4; ++kk) {
      s16x8 av = Tl[kk * 64 + l];
      acc0 = __builtin_amdgcn_mfma_f32_16x16x32_bf16(av, Wl[((w * 2 + 0) * 4 + kk) * 64 + l], acc0, 0, 0, 0);
      acc1 = __builtin_amdgcn_mfma_f32_16x16x32_bf16(av, Wl[((w * 2 + 1) * 4 + kk) * 64 + l], acc1, 0, 0, 0);
    }
    int colb = w * 32 + (l & 15);
    int rowb = (l >> 4) * 4;
#pragma unroll
    for (int p = 0; p < 4; ++p) {
      int bb = base + rowb + p;
      int d = sidx[2 * bb];   // scatter by i
      unsafeAtomicAdd(agg2 + (size_t)d * SZ + colb,      fmaxf(acc0[p], 0.f));
      unsafeAtomicAdd(agg2 + (size_t)d * SZ + colb + 16, fmaxf(acc1[p], 0.f));
    }
    __syncthreads();
  }
}

// update1: out = x + agg@W1 + b1 ; h2 = LN(out)
__global__ __launch_bounds__(256) void k_update1(const float* __restrict__ agg,
                                                 const float* __restrict__ x,
                                                 const float* __restrict__ b1,
                                                 const float* __restrict__ lnw,
                                                 const float* __restrict__ lnb,
                                                 const s16x8* __restrict__ Wt,
                                                 float* __restrict__ out,
                                                 unsigned short* __restrict__ h2) {
  __shared__ s16x8 Wl[2048];
  __shared__ s16x8 Tl[256];
  __shared__ float Xl[16][128];
  int tid = threadIdx.x;
  for (int i = tid; i < 2048; i += 256) Wl[i] = Wt[i];
  __syncthreads();
  int r = tid >> 4, kc = tid & 15;
  int w = tid >> 6, l = tid & 63;
  int colb = w * 32 + (l & 15);
  int rowb = (l >> 4) * 4;
  float bb0 = b1[colb], bb1 = b1[colb + 16];
  float2 g2 = *(const float2*)(lnw + l * 2);
  float2 be2 = *(const float2*)(lnb + l * 2);
  for (int tile = blockIdx.x; tile < NATOMS / 16; tile += gridDim.x) {
    int base = tile * 16;
    int a = base + r;
    float qb[8];
    *(float4*)&qb[0] = *(const float4*)(agg + (size_t)a * SZ + kc * 8);
    *(float4*)&qb[4] = *(const float4*)(agg + (size_t)a * SZ + kc * 8 + 4);
    s16x8 tv;
#pragma unroll
    for (int i = 0; i < 8; ++i) tv[i] = (short)f2bf(qb[i]);
    Tl[(kc >> 2) * 64 + (kc & 3) * 16 + r] = tv;
    __syncthreads();
    f32x4 acc0 = {0.f, 0.f, 0.f, 0.f}, acc1 = {0.f, 0.f, 0.f, 0.f};
#pragma unroll
    for (int kk = 0; kk < 4; ++kk) {
      s16x8 av = Tl[kk * 64 + l];
      acc0 = __builtin_amdgcn_mfma_f32_16x16x32_bf16(av, Wl[((w * 2 + 0) * 4 + kk) * 64 + l], acc0, 0, 0, 0);
      acc1 = __builtin_amdgcn_mfma_f32_16x16x32_bf16(av, Wl[((w * 2 + 1) * 4 + kk) * 64 + l], acc1, 0, 0, 0);
    }
#pragma unroll
    for (int p = 0; p < 4; ++p) {
      int atom = base + rowb + p;
      float v0 = acc0[p] + bb0 + x[(size_t)atom * SZ + colb];
      float v1 = acc1[p] + bb1 + x[(size_t)atom * SZ + colb + 16];
      out[(size_t)atom * SZ + colb] = v0;
      out[(size_t)atom * SZ + colb + 16] = v1;
      Xl[rowb + p][colb] = v0;
      Xl[rowb + p][colb + 16] = v1;
    }
    __syncthreads();
#pragma unroll
    for (int rr = 0; rr < 4; ++rr) {
      int rw = w * 4 + rr;
      float2 v = *(const float2*)&Xl[rw][l * 2];
      float s = v.x + v.y, sq = v.x * v.x + v.y * v.y;
#pragma unroll
      for (int off = 32; off; off >>= 1) { s += __shfl_xor(s, off); sq += __shfl_xor(sq, off); }
      float m = s * 0.0078125f;
      float var = sq * 0.0078125f - m * m;
      float rstd = rsqrtf(var + 1e-5f);
      float y0 = (v.x - m) * rstd * g2.x + be2.x;
      float y1 = (v.y - m) * rstd * g2.y + be2.y;
      unsigned pack = (unsigned)f2bf(y0) | ((unsigned)f2bf(y1) << 16);
      ((unsigned*)h2)[(size_t)(base + rw) * 64 + l] = pack;
    }
    __syncthreads();
  }
}

// update2: out += agg2@W2 + b2
__global__ __launch_bounds__(256) void k_update2(const float* __restrict__ agg2,
                                                 const float* __restrict__ b2,
                                                 const s16x8* __restrict__ Wt,
                                                 float* __restrict__ out) {
  __shared__ s16x8 Wl[2048];
  __shared__ s16x8 Tl[256];
  int tid = threadIdx.x;
  for (int i = tid; i < 2048; i += 256) Wl[i] = Wt[i];
  __syncthreads();
  int r = tid >> 4, kc = tid & 15;
  int w = tid >> 6, l = tid & 63;
  int colb = w * 32 + (l & 15);
  int rowb = (l >> 4) * 4;
  float bb0 = b2[colb], bb1 = b2[colb + 16];
  for (int tile = blockIdx.x; tile < NATOMS / 16; tile += gridDim.x) {
    int base = tile * 16;
    int a = base + r;
    float qb[8];
    *(float4*)&qb[0] = *(const float4*)(agg2 + (size_t)a * SZ + kc * 8);
    *(float4*)&qb[4] = *(const float4*)(agg2 + (size_t)a * SZ + kc * 8 + 4);
    s16x8 tv;
#pragma unroll
    for (int i = 0; i < 8; ++i) tv[i] = (short)f2bf(qb[i]);
    Tl[(kc >> 2) * 64 + (kc & 3) * 16 + r] = tv;
    __syncthreads();
    f32x4 acc0 = {0.f, 0.f, 0.f, 0.f}, acc1 = {0.f, 0.f, 0.f, 0.f};
#pragma unroll
    for (int kk = 0; kk < 4; ++kk) {
      s16x8 av = Tl[kk * 64 + l];
      acc0 = __builtin_amdgcn_mfma_f32_16x16x32_bf16(av, Wl[((w * 2 + 0) * 4 + kk) * 64 + l], acc0, 0, 0, 0);
      acc1 = __builtin_amdgcn_mfma_f32_16x16x32_bf16(av, Wl[((w * 2 + 1) * 4 + kk) * 64 + l], acc1, 0, 0, 0);
    }
#pragma unroll
    for (int p = 0; p < 4; ++p) {
      int atom = base + rowb + p;
      out[(size_t)atom * SZ + colb]      += acc0[p] + bb0;
      out[(size_t)atom * SZ + colb + 16] += acc1[p] + bb1;
    }
    __syncthreads();
  }
}

extern "C" void kernel_launch(void* const* d_in, const int* in_sizes, int n_in,
                              void* d_out, int out_size, void* d_ws, size_t ws_size,
                              hipStream_t stream) {
  (void)in_sizes; (void)n_in; (void)out_size; (void)ws_size;
  const float* x        = (const float*)d_in[0];
  const float* bond_x   = (const float*)d_in[1];
  const float* sc_pair  = (const float*)d_in[2];
  const float* angles   = (const float*)d_in[3];
  const float* W_bm     = (const float*)d_in[4];
  const float* W_sc     = (const float*)d_in[5];
  const float* W1       = (const float*)d_in[6];
  const float* b1       = (const float*)d_in[7];
  const float* W2       = (const float*)d_in[8];
  const float* b2       = (const float*)d_in[9];
  const float* ln1w     = (const float*)d_in[10];
  const float* ln1b     = (const float*)d_in[11];
  const float* ln2w     = (const float*)d_in[12];
  const float* ln2b     = (const float*)d_in[13];
  const int* bond_idx   = (const int*)d_in[15];
  const int* sc_idx     = (const int*)d_in[16];
  const int* ang_idx    = (const int*)d_in[17];
  float* out = (float*)d_out;
  char* ws = (char*)d_ws;

  float* bond_ang = (float*)(ws + BOND_ANG_OFF);
  float* agg      = (float*)(ws + AGG_OFF);
  float* agg2     = (float*)(ws + AGG2_OFF);
  unsigned short* hbuf  = (unsigned short*)(ws + H_OFF);
  unsigned short* h2buf = (unsigned short*)(ws + H2_OFF);
  s16x8* wt_bm = (s16x8*)(ws + WT_BM_OFF);
  s16x8* wt_sc = (s16x8*)(ws + WT_SC_OFF);
  s16x8* wt1   = (s16x8*)(ws + WT1_OFF);
  s16x8* wt2   = (s16x8*)(ws + WT2_OFF);

  hipMemsetAsync(ws, 0, ZERO_BYTES, stream);

  k_prep_w<<<8, 256, 0, stream>>>(W_bm, wt_bm);
  k_prep_w<<<8, 256, 0, stream>>>(W_sc, wt_sc);
  k_prep_w<<<8, 256, 0, stream>>>(W1, wt1);
  k_prep_w<<<8, 256, 0, stream>>>(W2, wt2);

  k_ln<<<NATOMS / 4, 256, 0, stream>>>(x, ln1w, ln1b, hbuf);
  k_angle_scatter<<<(NANG * 32) / 256, 256, 0, stream>>>(angles, ang_idx, bond_ang);
  k_msg1<<<2048, 256, 0, stream>>>(hbuf, bond_x, bond_ang, bond_idx, wt_bm, agg);
  k_update1<<<1024, 256, 0, stream>>>(agg, x, b1, ln2w, ln2b, wt1, out, h2buf);
  k_msg2<<<2048, 256, 0, stream>>>(h2buf, sc_pair, sc_idx, wt_sc, agg2);
  k_update2<<<1024, 256, 0, stream>>>(agg2, b2, wt2, out);
}

// Round 2
// 655.487 us; speedup vs baseline: 2.8221x; 2.8221x over previous
//
#include <hip/hip_runtime.h>

#define SZ 128
#define NATOMS 100000
#define NBONDS 400000
#define NPAIRS 400000
#define NANG   800000

typedef float f32x4 __attribute__((ext_vector_type(4)));
typedef short s16x8 __attribute__((ext_vector_type(8)));

__device__ __forceinline__ unsigned short f2bf(float f) {
  union { float f; unsigned u; } v; v.f = f;
  unsigned r = v.u + 0x7FFFu + ((v.u >> 16) & 1u);
  return (unsigned short)(r >> 16);
}
__device__ __forceinline__ float bf2f(unsigned short h) {
  union { unsigned u; float f; } v; v.u = ((unsigned)h) << 16;
  return v.f;
}

// ---- workspace layout (bytes) ----
#define AGG_OFF      0ull
#define AGG2_OFF     51200000ull
#define CNT_OFF      102400000ull
#define FILL_OFF     104000000ull
#define ZERO_BYTES   105600000ull   // agg + agg2 + cnt + fill (contiguous from 0)
#define START_OFF    105600000ull
#define ALIST_OFF    107200000ull
#define BSUM_OFF     110400000ull
#define H_OFF        110404096ull
#define H2_OFF       136004096ull
#define WT_BM_OFF    161604096ull
#define WT_SC_OFF    (WT_BM_OFF + 32768ull)
#define WT1_OFF      (WT_SC_OFF + 32768ull)
#define WT2_OFF      (WT1_OFF + 32768ull)

#define SCAN_EPB 1024
#define NSCAN_BLOCKS ((NBONDS + SCAN_EPB - 1) / SCAN_EPB)   // 391

// Pack W (f32 [k][n], k-major) into bf16 B-fragment order:
// chunk cid = (nt8*4 + kk)*64 + l holds W[kk*32+(l>>4)*8 + i][nt8*16 + (l&15)], i=0..7
__global__ __launch_bounds__(256) void k_prep_w(const float* __restrict__ W,
                                                s16x8* __restrict__ Wt) {
  int cid = blockIdx.x * 256 + threadIdx.x;   // 0..2047
  int nt8 = cid >> 8, kk = (cid >> 6) & 3, l = cid & 63;
  int col = nt8 * 16 + (l & 15);
  int k0  = kk * 32 + (l >> 4) * 8;
  s16x8 v;
#pragma unroll
  for (int i = 0; i < 8; ++i) v[i] = (short)f2bf(W[(k0 + i) * SZ + col]);
  Wt[cid] = v;
}

// LayerNorm f32 -> bf16, one wave per row (4 rows / 256-thread block)
__global__ __launch_bounds__(256) void k_ln(const float* __restrict__ x,
                                            const float* __restrict__ g,
                                            const float* __restrict__ bvec,
                                            unsigned short* __restrict__ hout) {
  int row  = blockIdx.x * 4 + (threadIdx.x >> 6);
  int lane = threadIdx.x & 63;
  float2 v = *(const float2*)(x + (size_t)row * SZ + lane * 2);
  float s = v.x + v.y, sq = v.x * v.x + v.y * v.y;
#pragma unroll
  for (int off = 32; off; off >>= 1) { s += __shfl_xor(s, off); sq += __shfl_xor(sq, off); }
  float m = s * 0.0078125f;
  float var = sq * 0.0078125f - m * m;
  float rstd = rsqrtf(var + 1e-5f);
  float2 gv = *(const float2*)(g + lane * 2);
  float2 bv = *(const float2*)(bvec + lane * 2);
  float y0 = (v.x - m) * rstd * gv.x + bv.x;
  float y1 = (v.y - m) * rstd * gv.y + bv.y;
  unsigned pack = (unsigned)f2bf(y0) | ((unsigned)f2bf(y1) << 16);
  ((unsigned*)hout)[(size_t)row * 64 + lane] = pack;
}

// ---- CSR build for angles -> bonds ----
__global__ __launch_bounds__(256) void k_hist(const int* __restrict__ aidx,
                                              int* __restrict__ cnt) {
  int id = blockIdx.x * 256 + threadIdx.x;
  if (id < NANG) atomicAdd(&cnt[aidx[id]], 1);
}

// per-block exclusive scan: writes local-exclusive to start[], block total to bsum[]
__global__ __launch_bounds__(256) void k_scan1(const int* __restrict__ cnt,
                                               int* __restrict__ start,
                                               int* __restrict__ bsum) {
  __shared__ int wsum[4];
  int tid = threadIdx.x, bid = blockIdx.x;
  int base = bid * SCAN_EPB + tid * 4;
  int4 c;
  if (base + 3 < NBONDS) {
    c = *(const int4*)(cnt + base);
  } else {
    c.x = (base + 0 < NBONDS) ? cnt[base + 0] : 0;
    c.y = (base + 1 < NBONDS) ? cnt[base + 1] : 0;
    c.z = (base + 2 < NBONDS) ? cnt[base + 2] : 0;
    c.w = (base + 3 < NBONDS) ? cnt[base + 3] : 0;
  }
  int tsum = c.x + c.y + c.z + c.w;
  int lane = tid & 63, wid = tid >> 6;
  int inc = tsum;
#pragma unroll
  for (int off = 1; off < 64; off <<= 1) {
    int o = __shfl_up(inc, off);
    if (lane >= off) inc += o;
  }
  if (lane == 63) wsum[wid] = inc;
  __syncthreads();
  int woff = 0;
#pragma unroll
  for (int wq = 0; wq < 4; ++wq) { if (wq < wid) woff += wsum[wq]; }
  int s0 = woff + inc - tsum;     // exclusive prefix for this thread
  if (base + 0 < NBONDS) { start[base + 0] = s0; } s0 += c.x;
  if (base + 1 < NBONDS) { start[base + 1] = s0; } s0 += c.y;
  if (base + 2 < NBONDS) { start[base + 2] = s0; } s0 += c.z;
  if (base + 3 < NBONDS) { start[base + 3] = s0; }
  if (tid == 255) {
    int tot = 0;
#pragma unroll
    for (int wq = 0; wq < 4; ++wq) tot += wsum[wq];
    bsum[bid] = tot;
  }
}

// single-block exclusive scan of bsum[n] (n <= 512)
__global__ __launch_bounds__(512) void k_scan2(int* __restrict__ bsum, int n) {
  __shared__ int tmp[2][512];
  int tid = threadIdx.x;
  tmp[0][tid] = (tid < n) ? bsum[tid] : 0;
  int pi = 0;
  for (int off = 1; off < 512; off <<= 1) {
    __syncthreads();
    int t = tmp[pi][tid];
    if (tid >= off) t += tmp[pi][tid - off];
    tmp[pi ^ 1][tid] = t;
    pi ^= 1;
  }
  __syncthreads();
  if (tid < n) bsum[tid] = (tid == 0) ? 0 : tmp[pi][tid - 1];
}

__global__ __launch_bounds__(256) void k_scan_add(int* __restrict__ start,
                                                  const int* __restrict__ bsum) {
  int id = blockIdx.x * 256 + threadIdx.x;
  if (id < NBONDS) start[id] += bsum[id / SCAN_EPB];
}

__global__ __launch_bounds__(256) void k_fill(const int* __restrict__ aidx,
                                              const int* __restrict__ start,
                                              int* __restrict__ fill,
                                              int* __restrict__ alist) {
  int id = blockIdx.x * 256 + threadIdx.x;
  if (id < NANG) {
    int b = aidx[id];
    int p = atomicAdd(&fill[b], 1);
    alist[start[b] + p] = id;
  }
}

// msg1: agg[dst] += relu((h[src] + bond_x + segsum(angles)) @ W_bm), angle sum fused via CSR
__global__ __launch_bounds__(256) void k_msg1(const unsigned short* __restrict__ h,
                                              const float* __restrict__ bx,
                                              const float* __restrict__ angles,
                                              const int* __restrict__ start,
                                              const int* __restrict__ cnt,
                                              const int* __restrict__ alist,
                                              const int* __restrict__ bidx,
                                              const s16x8* __restrict__ Wt,
                                              float* __restrict__ agg) {
  __shared__ s16x8 Wl[2048];   // 32KB, B-fragment order
  __shared__ s16x8 Tl[256];    // 4KB, A-fragment order (16 rows x 128 k)
  int tid = threadIdx.x;
  for (int i = tid; i < 2048; i += 256) Wl[i] = Wt[i];
  __syncthreads();
  int r = tid >> 4, kc = tid & 15;
  int w = tid >> 6, l = tid & 63;
  for (int tile = blockIdx.x; tile < NBONDS / 16; tile += gridDim.x) {
    int base = tile * 16;
    int b = base + r;
    int sidx = bidx[2 * b];
    uint4 hv = *(const uint4*)(h + (size_t)sidx * SZ + kc * 8);
    const unsigned short* hp = (const unsigned short*)&hv;
    float xb[8];
    *(float4*)&xb[0] = *(const float4*)(bx + (size_t)b * SZ + kc * 8);
    *(float4*)&xb[4] = *(const float4*)(bx + (size_t)b * SZ + kc * 8 + 4);
    // fused CSR angle gather-sum
    float ab[8] = {0.f, 0.f, 0.f, 0.f, 0.f, 0.f, 0.f, 0.f};
    int s0 = start[b], nc = cnt[b];
    for (int t = 0; t < nc; ++t) {
      int ar = alist[s0 + t];
      const float* ap = angles + (size_t)ar * SZ + kc * 8;
      float4 u0 = *(const float4*)ap;
      float4 u1 = *(const float4*)(ap + 4);
      ab[0] += u0.x; ab[1] += u0.y; ab[2] += u0.z; ab[3] += u0.w;
      ab[4] += u1.x; ab[5] += u1.y; ab[6] += u1.z; ab[7] += u1.w;
    }
    s16x8 tv;
#pragma unroll
    for (int i = 0; i < 8; ++i) tv[i] = (short)f2bf(bf2f(hp[i]) + xb[i] + ab[i]);
    Tl[(kc >> 2) * 64 + (kc & 3) * 16 + r] = tv;
    __syncthreads();
    f32x4 acc0 = {0.f, 0.f, 0.f, 0.f}, acc1 = {0.f, 0.f, 0.f, 0.f};
#pragma unroll
    for (int kk = 0; kk < 4; ++kk) {
      s16x8 av = Tl[kk * 64 + l];
      acc0 = __builtin_amdgcn_mfma_f32_16x16x32_bf16(av, Wl[((w * 2 + 0) * 4 + kk) * 64 + l], acc0, 0, 0, 0);
      acc1 = __builtin_amdgcn_mfma_f32_16x16x32_bf16(av, Wl[((w * 2 + 1) * 4 + kk) * 64 + l], acc1, 0, 0, 0);
    }
    int colb = w * 32 + (l & 15);
    int rowb = (l >> 4) * 4;
#pragma unroll
    for (int p = 0; p < 4; ++p) {
      int bb = base + rowb + p;
      int d = bidx[2 * bb + 1];
      unsafeAtomicAdd(agg + (size_t)d * SZ + colb,      fmaxf(acc0[p], 0.f));
      unsafeAtomicAdd(agg + (size_t)d * SZ + colb + 16, fmaxf(acc1[p], 0.f));
    }
    __syncthreads();
  }
}

// msg2: agg2[i] += relu((h2[i] + h2[j] + sc_pair) @ W_sc)
__global__ __launch_bounds__(256) void k_msg2(const unsigned short* __restrict__ h2,
                                              const float* __restrict__ scp,
                                              const int* __restrict__ sidx,
                                              const s16x8* __restrict__ Wt,
                                              float* __restrict__ agg2) {
  __shared__ s16x8 Wl[2048];
  __shared__ s16x8 Tl[256];
  int tid = threadIdx.x;
  for (int i = tid; i < 2048; i += 256) Wl[i] = Wt[i];
  __syncthreads();
  int r = tid >> 4, kc = tid & 15;
  int w = tid >> 6, l = tid & 63;
  for (int tile = blockIdx.x; tile < NPAIRS / 16; tile += gridDim.x) {
    int base = tile * 16;
    int b = base + r;
    int i0 = sidx[2 * b], j0 = sidx[2 * b + 1];
    uint4 hv1 = *(const uint4*)(h2 + (size_t)i0 * SZ + kc * 8);
    uint4 hv2 = *(const uint4*)(h2 + (size_t)j0 * SZ + kc * 8);
    const unsigned short* hp1 = (const unsigned short*)&hv1;
    const unsigned short* hp2 = (const unsigned short*)&hv2;
    float sb[8];
    *(float4*)&sb[0] = *(const float4*)(scp + (size_t)b * SZ + kc * 8);
    *(float4*)&sb[4] = *(const float4*)(scp + (size_t)b * SZ + kc * 8 + 4);
    s16x8 tv;
#pragma unroll
    for (int i = 0; i < 8; ++i) tv[i] = (short)f2bf(bf2f(hp1[i]) + bf2f(hp2[i]) + sb[i]);
    Tl[(kc >> 2) * 64 + (kc & 3) * 16 + r] = tv;
    __syncthreads();
    f32x4 acc0 = {0.f, 0.f, 0.f, 0.f}, acc1 = {0.f, 0.f, 0.f, 0.f};
#pragma unroll
    for (int kk = 0; kk < 4; ++kk) {
      s16x8 av = Tl[kk * 64 + l];
      acc0 = __builtin_amdgcn_mfma_f32_16x16x32_bf16(av, Wl[((w * 2 + 0) * 4 + kk) * 64 + l], acc0, 0, 0, 0);
      acc1 = __builtin_amdgcn_mfma_f32_16x16x32_bf16(av, Wl[((w * 2 + 1) * 4 + kk) * 64 + l], acc1, 0, 0, 0);
    }
    int colb = w * 32 + (l & 15);
    int rowb = (l >> 4) * 4;
#pragma unroll
    for (int p = 0; p < 4; ++p) {
      int bb = base + rowb + p;
      int d = sidx[2 * bb];   // scatter by i
      unsafeAtomicAdd(agg2 + (size_t)d * SZ + colb,      fmaxf(acc0[p], 0.f));
      unsafeAtomicAdd(agg2 + (size_t)d * SZ + colb + 16, fmaxf(acc1[p], 0.f));
    }
    __syncthreads();
  }
}

// update1: out = x + agg@W1 + b1 ; h2 = LN(out)
__global__ __launch_bounds__(256) void k_update1(const float* __restrict__ agg,
                                                 const float* __restrict__ x,
                                                 const float* __restrict__ b1,
                                                 const float* __restrict__ lnw,
                                                 const float* __restrict__ lnb,
                                                 const s16x8* __restrict__ Wt,
                                                 float* __restrict__ out,
                                                 unsigned short* __restrict__ h2) {
  __shared__ s16x8 Wl[2048];
  __shared__ s16x8 Tl[256];
  __shared__ float Xl[16][128];
  int tid = threadIdx.x;
  for (int i = tid; i < 2048; i += 256) Wl[i] = Wt[i];
  __syncthreads();
  int r = tid >> 4, kc = tid & 15;
  int w = tid >> 6, l = tid & 63;
  int colb = w * 32 + (l & 15);
  int rowb = (l >> 4) * 4;
  float bb0 = b1[colb], bb1 = b1[colb + 16];
  float2 g2 = *(const float2*)(lnw + l * 2);
  float2 be2 = *(const float2*)(lnb + l * 2);
  for (int tile = blockIdx.x; tile < NATOMS / 16; tile += gridDim.x) {
    int base = tile * 16;
    int a = base + r;
    float qb[8];
    *(float4*)&qb[0] = *(const float4*)(agg + (size_t)a * SZ + kc * 8);
    *(float4*)&qb[4] = *(const float4*)(agg + (size_t)a * SZ + kc * 8 + 4);
    s16x8 tv;
#pragma unroll
    for (int i = 0; i < 8; ++i) tv[i] = (short)f2bf(qb[i]);
    Tl[(kc >> 2) * 64 + (kc & 3) * 16 + r] = tv;
    __syncthreads();
    f32x4 acc0 = {0.f, 0.f, 0.f, 0.f}, acc1 = {0.f, 0.f, 0.f, 0.f};
#pragma unroll
    for (int kk = 0; kk < 4; ++kk) {
      s16x8 av = Tl[kk * 64 + l];
      acc0 = __builtin_amdgcn_mfma_f32_16x16x32_bf16(av, Wl[((w * 2 + 0) * 4 + kk) * 64 + l], acc0, 0, 0, 0);
      acc1 = __builtin_amdgcn_mfma_f32_16x16x32_bf16(av, Wl[((w * 2 + 1) * 4 + kk) * 64 + l], acc1, 0, 0, 0);
    }
#pragma unroll
    for (int p = 0; p < 4; ++p) {
      int atom = base + rowb + p;
      float v0 = acc0[p] + bb0 + x[(size_t)atom * SZ + colb];
      float v1 = acc1[p] + bb1 + x[(size_t)atom * SZ + colb + 16];
      out[(size_t)atom * SZ + colb] = v0;
      out[(size_t)atom * SZ + colb + 16] = v1;
      Xl[rowb + p][colb] = v0;
      Xl[rowb + p][colb + 16] = v1;
    }
    __syncthreads();
#pragma unroll
    for (int rr = 0; rr < 4; ++rr) {
      int rw = w * 4 + rr;
      float2 v = *(const float2*)&Xl[rw][l * 2];
      float s = v.x + v.y, sq = v.x * v.x + v.y * v.y;
#pragma unroll
      for (int off = 32; off; off >>= 1) { s += __shfl_xor(s, off); sq += __shfl_xor(sq, off); }
      float m = s * 0.0078125f;
      float var = sq * 0.0078125f - m * m;
      float rstd = rsqrtf(var + 1e-5f);
      float y0 = (v.x - m) * rstd * g2.x + be2.x;
      float y1 = (v.y - m) * rstd * g2.y + be2.y;
      unsigned pack = (unsigned)f2bf(y0) | ((unsigned)f2bf(y1) << 16);
      ((unsigned*)h2)[(size_t)(base + rw) * 64 + l] = pack;
    }
    __syncthreads();
  }
}

// update2: out += agg2@W2 + b2
__global__ __launch_bounds__(256) void k_update2(const float* __restrict__ agg2,
                                                 const float* __restrict__ b2,
                                                 const s16x8* __restrict__ Wt,
                                                 float* __restrict__ out) {
  __shared__ s16x8 Wl[2048];
  __shared__ s16x8 Tl[256];
  int tid = threadIdx.x;
  for (int i = tid; i < 2048; i += 256) Wl[i] = Wt[i];
  __syncthreads();
  int r = tid >> 4, kc = tid & 15;
  int w = tid >> 6, l = tid & 63;
  int colb = w * 32 + (l & 15);
  int rowb = (l >> 4) * 4;
  float bb0 = b2[colb], bb1 = b2[colb + 16];
  for (int tile = blockIdx.x; tile < NATOMS / 16; tile += gridDim.x) {
    int base = tile * 16;
    int a = base + r;
    float qb[8];
    *(float4*)&qb[0] = *(const float4*)(agg2 + (size_t)a * SZ + kc * 8);
    *(float4*)&qb[4] = *(const float4*)(agg2 + (size_t)a * SZ + kc * 8 + 4);
    s16x8 tv;
#pragma unroll
    for (int i = 0; i < 8; ++i) tv[i] = (short)f2bf(qb[i]);
    Tl[(kc >> 2) * 64 + (kc & 3) * 16 + r] = tv;
    __syncthreads();
    f32x4 acc0 = {0.f, 0.f, 0.f, 0.f}, acc1 = {0.f, 0.f, 0.f, 0.f};
#pragma unroll
    for (int kk = 0; kk < 4; ++kk) {
      s16x8 av = Tl[kk * 64 + l];
      acc0 = __builtin_amdgcn_mfma_f32_16x16x32_bf16(av, Wl[((w * 2 + 0) * 4 + kk) * 64 + l], acc0, 0, 0, 0);
      acc1 = __builtin_amdgcn_mfma_f32_16x16x32_bf16(av, Wl[((w * 2 + 1) * 4 + kk) * 64 + l], acc1, 0, 0, 0);
    }
#pragma unroll
    for (int p = 0; p < 4; ++p) {
      int atom = base + rowb + p;
      out[(size_t)atom * SZ + colb]      += acc0[p] + bb0;
      out[(size_t)atom * SZ + colb + 16] += acc1[p] + bb1;
    }
    __syncthreads();
  }
}

extern "C" void kernel_launch(void* const* d_in, const int* in_sizes, int n_in,
                              void* d_out, int out_size, void* d_ws, size_t ws_size,
                              hipStream_t stream) {
  (void)in_sizes; (void)n_in; (void)out_size; (void)ws_size;
  const float* x        = (const float*)d_in[0];
  const float* bond_x   = (const float*)d_in[1];
  const float* sc_pair  = (const float*)d_in[2];
  const float* angles   = (const float*)d_in[3];
  const float* W_bm     = (const float*)d_in[4];
  const float* W_sc     = (const float*)d_in[5];
  const float* W1       = (const float*)d_in[6];
  const float* b1       = (const float*)d_in[7];
  const float* W2       = (const float*)d_in[8];
  const float* b2       = (const float*)d_in[9];
  const float* ln1w     = (const float*)d_in[10];
  const float* ln1b     = (const float*)d_in[11];
  const float* ln2w     = (const float*)d_in[12];
  const float* ln2b     = (const float*)d_in[13];
  const int* bond_idx   = (const int*)d_in[15];
  const int* sc_idx     = (const int*)d_in[16];
  const int* ang_idx    = (const int*)d_in[17];
  float* out = (float*)d_out;
  char* ws = (char*)d_ws;

  float* agg      = (float*)(ws + AGG_OFF);
  float* agg2     = (float*)(ws + AGG2_OFF);
  int*   cnt      = (int*)(ws + CNT_OFF);
  int*   fill     = (int*)(ws + FILL_OFF);
  int*   start    = (int*)(ws + START_OFF);
  int*   alist    = (int*)(ws + ALIST_OFF);
  int*   bsum     = (int*)(ws + BSUM_OFF);
  unsigned short* hbuf  = (unsigned short*)(ws + H_OFF);
  unsigned short* h2buf = (unsigned short*)(ws + H2_OFF);
  s16x8* wt_bm = (s16x8*)(ws + WT_BM_OFF);
  s16x8* wt_sc = (s16x8*)(ws + WT_SC_OFF);
  s16x8* wt1   = (s16x8*)(ws + WT1_OFF);
  s16x8* wt2   = (s16x8*)(ws + WT2_OFF);

  hipMemsetAsync(ws, 0, ZERO_BYTES, stream);

  k_prep_w<<<8, 256, 0, stream>>>(W_bm, wt_bm);
  k_prep_w<<<8, 256, 0, stream>>>(W_sc, wt_sc);
  k_prep_w<<<8, 256, 0, stream>>>(W1, wt1);
  k_prep_w<<<8, 256, 0, stream>>>(W2, wt2);

  // CSR build: angles -> bonds
  k_hist<<<(NANG + 255) / 256, 256, 0, stream>>>(ang_idx, cnt);
  k_scan1<<<NSCAN_BLOCKS, 256, 0, stream>>>(cnt, start, bsum);
  k_scan2<<<1, 512, 0, stream>>>(bsum, NSCAN_BLOCKS);
  k_scan_add<<<(NBONDS + 255) / 256, 256, 0, stream>>>(start, bsum);
  k_fill<<<(NANG + 255) / 256, 256, 0, stream>>>(ang_idx, start, fill, alist);

  k_ln<<<NATOMS / 4, 256, 0, stream>>>(x, ln1w, ln1b, hbuf);
  k_msg1<<<2048, 256, 0, stream>>>(hbuf, bond_x, angles, start, cnt, alist, bond_idx, wt_bm, agg);
  k_update1<<<1024, 256, 0, stream>>>(agg, x, b1, ln2w, ln2b, wt1, out, h2buf);
  k_msg2<<<2048, 256, 0, stream>>>(h2buf, sc_pair, sc_idx, wt_sc, agg2);
  k_update2<<<1024, 256, 0, stream>>>(agg2, b2, wt2, out);
}